// Round 10
// baseline (380.501 us; speedup 1.0000x reference)
//
#include <hip/hip_runtime.h>

// MemoryReader: B=4, CK=64, N=8192, M=1024, CV=512. Inputs fp32, output fp32.
// logits s[n,m] = (2*mk.qk - |mk|^2)/8; softmax over n; out = mv @ P.
// R15/R16: PASSED, k_main 201us, grid 512, 2 barriers/step, latency-bound at
//   2 waves/SIMD (all pipes idle; R16 no-vmcnt-drain was neutral).
// R17: n-split + pacc round-trip REGRESSED (297us): FETCH 38->108MB, WRITE
//   8->121MB — same failure as R7 (L2 thrash + partial traffic). Lesson:
//   occupancy must come from inside the block, not from splitting N.
// R18: producer/consumer wave specialization. 512-thread blocks, grid 512
//   (unchanged streaming -> unchanged 38MB FETCH), 2 blocks/CU = 16 waves/CU.
//   Waves 0-3: GEMM1(step s) -> P into lds_p[s&1] (R15-pinned layout).
//   Waves 4-7: GEMM2(step s-1) from lds_p[(s-1)&1] (R15-pinned pack8 x P-b128).
//   ONE barrier per step; phases overlap across wave groups; K/mv/asq register-
//   prefetched one step ahead within each role. Epilogue: producers atomicAdd
//   denom, consumers normalize+store. k_prep = exonerated LDS-transpose.

typedef unsigned short ushort_t;
typedef unsigned int uint_t;
typedef __attribute__((ext_vector_type(8))) short short8;
typedef __attribute__((ext_vector_type(4))) float floatx4;

#define MFMA16(a, b, c) __builtin_amdgcn_mfma_f32_16x16x32_bf16((a), (b), (c), 0, 0, 0)

// Raw barrier: DS-ordering only; global register loads stay in flight.
#define BARRIER_DS() do {                                          \
    asm volatile("s_waitcnt lgkmcnt(0)" ::: "memory");             \
    __builtin_amdgcn_s_barrier();                                  \
} while (0)

__device__ __forceinline__ ushort_t f2b(float f) {
    uint_t b = __float_as_uint(f);
    b += 0x7FFFu + ((b >> 16) & 1u);   // RNE to bf16
    return (ushort_t)(b >> 16);
}

__device__ __forceinline__ short8 pack8(floatx4 a, floatx4 b) {
    short8 r;
    r[0] = (short)f2b(a[0]); r[1] = (short)f2b(a[1]);
    r[2] = (short)f2b(a[2]); r[3] = (short)f2b(a[3]);
    r[4] = (short)f2b(b[0]); r[5] = (short)f2b(b[1]);
    r[6] = (short)f2b(b[2]); r[7] = (short)f2b(b[3]);
    return r;
}

#define BB 4
#define CK 64
#define NN 8192
#define MM 1024
#define CV 512
#define NSTEP 128     // 64-token steps over full n-range

// ---- module-scope scratch (fully rewritten every call) ----
__device__ __align__(16) ushort_t g_mkT[BB * NN * CK];   // 4 MiB bf16 mk^T [b][n][c]
__device__ __align__(16) float    g_asq8[BB * NN];       // 128 KiB (sum mk^2)/8

// ---------------------------------------------------------------------------
// K0 (LDS-transpose, exonerated by R13/R14 + passed in R17): block=(b, 64-n
// tile). Phase1: thread (c=t>>2, seg=t&3) loads 16 contiguous fp32 of row c ->
// lds_t[n][c]. Phase2: thread (n=t>>2, seg) reads 16 contiguous c, f2b, 32B
// store to g_mkT; |a|^2 partial + shfl_xor(1,2) -> g_asq8.
// ---------------------------------------------------------------------------
__global__ __launch_bounds__(256) void k_prep(const float* __restrict__ mk) {
    __shared__ float lds_t[64][68];
    int bx = blockIdx.x;
    int b = bx >> 7;             // 0..3
    int nt = bx & 127;           // 0..127
    int tid = threadIdx.x;
    int cc = tid >> 2, seg = tid & 3;
    const float* src = mk + ((size_t)(b * CK + cc)) * NN + nt * 64 + seg * 16;
#pragma unroll
    for (int g = 0; g < 4; g++) {
        floatx4 v = *(const floatx4*)(src + g * 4);
        lds_t[seg * 16 + g * 4 + 0][cc] = v[0];
        lds_t[seg * 16 + g * 4 + 1][cc] = v[1];
        lds_t[seg * 16 + g * 4 + 2][cc] = v[2];
        lds_t[seg * 16 + g * 4 + 3][cc] = v[3];
    }
    __syncthreads();
    int n = tid >> 2;
    const float* row = &lds_t[n][seg * 16];
    float v[16];
#pragma unroll
    for (int i = 0; i < 16; i++) v[i] = row[i];
    float sq = 0.f;
#pragma unroll
    for (int i = 0; i < 16; i++) sq = fmaf(v[i], v[i], sq);
    sq += __shfl_xor(sq, 1, 64);
    sq += __shfl_xor(sq, 2, 64);
    uint4 q0, q1;
    q0.x = (uint_t)f2b(v[0])  | ((uint_t)f2b(v[1])  << 16);
    q0.y = (uint_t)f2b(v[2])  | ((uint_t)f2b(v[3])  << 16);
    q0.z = (uint_t)f2b(v[4])  | ((uint_t)f2b(v[5])  << 16);
    q0.w = (uint_t)f2b(v[6])  | ((uint_t)f2b(v[7])  << 16);
    q1.x = (uint_t)f2b(v[8])  | ((uint_t)f2b(v[9])  << 16);
    q1.y = (uint_t)f2b(v[10]) | ((uint_t)f2b(v[11]) << 16);
    q1.z = (uint_t)f2b(v[12]) | ((uint_t)f2b(v[13]) << 16);
    q1.w = (uint_t)f2b(v[14]) | ((uint_t)f2b(v[15]) << 16);
    ushort_t* dst = g_mkT + ((size_t)b * NN + nt * 64 + n) * CK + seg * 16;
    *(uint4*)dst = q0;
    *(uint4*)(dst + 8) = q1;
    if (seg == 0) g_asq8[(size_t)b * NN + nt * 64 + n] = sq * 0.125f;
}

// ---------------------------------------------------------------------------
// K1: grid 512 = mt16(16) x cs(8) x b(4); block 512 = 8 waves.
// Producers (wave 0-3, n-strip w*16): GEMM1 A=Q regs, B=K 16B stream ->
//   D[m=quad*4+r][n=l15]; p=exp(d/4-asq); f2b b16 -> lds_p[s&1][m][n] pitch 72.
// Consumers (wave 4-7, c-strip w*16): GEMM2 A=pack8(mv fp32 regs),
//   B=P b128 from lds_p[(s-1)&1] -> acc (c=quad*4+r, m=mt*16+l15).
// One BARRIER_DS per step. Registers double-buffered per role (A/B sets).
// ---------------------------------------------------------------------------

#define PFK(KD0, KD1, AD, sv) do {                                              \
    const ushort_t* kp = kbase + (size_t)(sv) * 64 * CK;                        \
    KD0 = *(const short8*)kp;                                                   \
    KD1 = *(const short8*)(kp + 32);                                            \
    AD  = asbase[(size_t)(sv) * 64];                                            \
} while (0)

#define PFM(MD0, MD1, MD2, MD3, sv) do {                                        \
    const float* mp = mvbase + (size_t)(sv) * 64;                               \
    MD0 = *(const floatx4*)(mp);                                                \
    MD1 = *(const floatx4*)(mp + 4);                                            \
    MD2 = *(const floatx4*)(mp + 32);                                           \
    MD3 = *(const floatx4*)(mp + 36);                                           \
} while (0)

#define PSTEP(KC0, KC1, AC, BUFID) do {                                         \
    _Pragma("unroll")                                                           \
    for (int mt = 0; mt < 4; mt++) {                                            \
        floatx4 d = (floatx4){0.f, 0.f, 0.f, 0.f};                              \
        d = MFMA16(qb0[mt], KC0, d);                                            \
        d = MFMA16(qb1[mt], KC1, d);                                            \
        _Pragma("unroll")                                                       \
        for (int r = 0; r < 4; r++) {                                           \
            float p = __expf(d[r] * 0.25f - AC);                                \
            dpart[mt][r] += p;                                                  \
            lds_p[BUFID][(mt * 16 + quad * 4 + r) * 72 + w * 16 + l15] = f2b(p); \
        }                                                                       \
    }                                                                           \
} while (0)

#define CSTEP(M0, M1, M2, M3, BUFID) do {                                       \
    short8 va0 = pack8(M0, M1);                                                 \
    short8 va1 = pack8(M2, M3);                                                 \
    _Pragma("unroll")                                                           \
    for (int mt = 0; mt < 4; mt++) {                                            \
        short8 pb0 = *(const short8*)&lds_p[BUFID][(mt * 16 + l15) * 72 + quad * 8];      \
        short8 pb1 = *(const short8*)&lds_p[BUFID][(mt * 16 + l15) * 72 + 32 + quad * 8]; \
        acc[mt] = MFMA16(va0, pb0, acc[mt]);                                    \
        acc[mt] = MFMA16(va1, pb1, acc[mt]);                                    \
    }                                                                           \
} while (0)

__global__ __launch_bounds__(512, 4) void k_main(const float* __restrict__ qk,
                                                 const float* __restrict__ mv,
                                                 float* __restrict__ out) {
    __shared__ __align__(16) ushort_t lds_p[2][64 * 72];   // 2 x 9 KiB P dbuf
    __shared__ float dn[64];                               // denom per m_loc

    int bx = blockIdx.x;
    int mt16 = bx >> 5;          // 0..15
    int cs = (bx >> 2) & 7;      // 0..7  (bx%8 const per (cs,b): XCD grouping)
    int b = bx & 3;              // 0..3
    int c0 = cs * 64;
    int m0 = mt16 * 64;

    int tid = threadIdx.x;
    int wid = tid >> 6;          // 0..7
    int w = wid & 3;             // role-local wave index
    bool prod = wid < 4;
    int lane = tid & 63;
    int quad = lane >> 4;
    int l15 = lane & 15;

    if (tid < 64) dn[tid] = 0.f;   // ordered before post-loop use by loop barriers

    // ---- role state ----
    short8 qb0[4], qb1[4];
    short8 kA0, kA1, kB0, kB1;
    float aA, aB;
    float dpart[4][4];
    floatx4 mA0, mA1, mA2, mA3, mB0, mB1, mB2, mB3;
    floatx4 acc[4];

    const ushort_t* kbase  = g_mkT + ((size_t)b * NN + w * 16 + l15) * CK + quad * 8;
    const float*    asbase = g_asq8 + (size_t)b * NN + w * 16 + l15;
    const float*    mvbase = mv + ((size_t)(b * CV + c0 + w * 16 + l15)) * NN + quad * 8;

    if (prod) {
        // Q fragments: 4 m-tiles x K=64 (A-operand rows m = mt*16 + l15)
#pragma unroll
        for (int mt = 0; mt < 4; mt++) {
#pragma unroll
            for (int j = 0; j < 8; j++) {
                qb0[mt][j] = (short)f2b(qk[(size_t)(b * CK + quad * 8 + j) * MM + m0 + mt * 16 + l15]);
                qb1[mt][j] = (short)f2b(qk[(size_t)(b * CK + 32 + quad * 8 + j) * MM + m0 + mt * 16 + l15]);
            }
        }
#pragma unroll
        for (int i = 0; i < 4; i++)
#pragma unroll
            for (int j = 0; j < 4; j++) dpart[i][j] = 0.f;
        PFK(kA0, kA1, aA, 0);
    } else {
#pragma unroll
        for (int i = 0; i < 4; i++) acc[i] = (floatx4){0.f, 0.f, 0.f, 0.f};
    }

    for (int sp = 0; sp < NSTEP / 2; sp++) {
        // ---- iter A: producer step 2sp (buf 0); consumer step 2sp-1 (buf 1) ----
        if (prod) {
            PFK(kB0, kB1, aB, sp * 2 + 1);
            PSTEP(kA0, kA1, aA, 0);
        } else {
            PFM(mA0, mA1, mA2, mA3, sp * 2);     // for window 2sp (used iter B)
            if (sp > 0) CSTEP(mB0, mB1, mB2, mB3, 1);
        }
        BARRIER_DS();
        // ---- iter B: producer step 2sp+1 (buf 1); consumer step 2sp (buf 0) ----
        if (prod) {
            if (sp + 1 < NSTEP / 2) PFK(kA0, kA1, aA, sp * 2 + 2);
            PSTEP(kB0, kB1, aB, 1);
        } else {
            PFM(mB0, mB1, mB2, mB3, sp * 2 + 1); // for window 2sp+1 (used next iter A)
            CSTEP(mA0, mA1, mA2, mA3, 0);
        }
        BARRIER_DS();
    }

    // ---- post-loop: producers reduce denom; consumers finish step 127 ----
    if (prod) {
#pragma unroll
        for (int mt = 0; mt < 4; mt++) {
#pragma unroll
            for (int r = 0; r < 4; r++) {
                float s = dpart[mt][r];
                s += __shfl_xor(s, 1, 64);
                s += __shfl_xor(s, 2, 64);
                s += __shfl_xor(s, 4, 64);
                s += __shfl_xor(s, 8, 64);
                if (l15 == 0) atomicAdd(&dn[mt * 16 + quad * 4 + r], s);
            }
        }
    } else {
        CSTEP(mB0, mB1, mB2, mB3, 1);   // window 127 (buf 1, written at sp=63 iter B)
    }
    __syncthreads();

    if (!prod) {
        float rdm[4];
#pragma unroll
        for (int mt = 0; mt < 4; mt++) rdm[mt] = 1.0f / dn[mt * 16 + l15];
#pragma unroll
        for (int mt = 0; mt < 4; mt++) {
#pragma unroll
            for (int r = 0; r < 4; r++) {
                size_t o = (size_t)(b * CV + c0 + w * 16 + quad * 4 + r) * MM
                         + m0 + mt * 16 + l15;
                out[o] = acc[mt][r] * rdm[mt];
            }
        }
    }
}

// ---------------------------------------------------------------------------
// launch — inputs identified BY SIZE.
// ---------------------------------------------------------------------------
extern "C" void kernel_launch(void* const* d_in, const int* in_sizes, int n_in,
                              void* d_out, int out_size, void* d_ws, size_t ws_size,
                              hipStream_t stream) {
    const float* mk = nullptr;   // 2,097,152
    const float* qk = nullptr;   //   262,144
    const float* mv = nullptr;   // 16,777,216
    for (int i = 0; i < n_in; i++) {
        if (in_sizes[i] == BB * CK * NN)      mk = (const float*)d_in[i];
        else if (in_sizes[i] == BB * CK * MM) qk = (const float*)d_in[i];
        else if (in_sizes[i] == BB * CV * NN) mv = (const float*)d_in[i];
    }
    float* out = (float*)d_out;
    (void)d_ws; (void)ws_size; (void)out_size;

    k_prep<<<BB * 128, 256, 0, stream>>>(mk);
    k_main<<<16 * 8 * BB, 512, 0, stream>>>(qk, mv, out);
}

// Round 12
// 295.792 us; speedup vs baseline: 1.2864x; 1.2864x over previous
//
#include <hip/hip_runtime.h>

// MemoryReader: B=4, CK=64, N=8192, M=1024, CV=512. Inputs fp32, output fp32.
// logits s[n,m] = (2*mk.qk - |mk|^2)/8; softmax over n; out = mv @ P.
// R15/R16: PASSED 201us k_main (grid 512, 4 waves, P via 9KB LDS, 2 barriers/
//   step, latency-bound at 2 waves/SIMD). R17 (n-split+pacc): 297us REGRESS
//   (L2 thrash + partial traffic). R18 (producer/consumer 8-wave): 316us
//   REGRESS (occupancy 44% but barrier-skew doubled; VALUBusy fell 37->24).
//   Lesson: this kernel's step time is latency-pinned ~3770cy; extra waves
//   only add sync skew. Durable fact: prep pass costs ~70us for 12MB traffic.
// R19: DELETE the prep pass. k_main reverts to R15/R16 shape; K-fragments load
//   directly from mk fp32 (16 scalar lane-coalesced loads/step/wave, register
//   dbuf one step ahead, f2b at consume); |a|^2 computed in-wave: quads of one
//   l15 column jointly hold all 64 c -> sum16 + shfl_xor(16,32), x0.125.
//   g_mkT/g_asq8/k_prep deleted; single-kernel launch. L2 class footprint:
//   mk[b] 2MB + mv slice 2MB = 4MB/XCD.
// R20: resubmit of R19 unchanged (container infra failed twice; never ran).

typedef unsigned short ushort_t;
typedef unsigned int uint_t;
typedef __attribute__((ext_vector_type(8))) short short8;
typedef __attribute__((ext_vector_type(4))) float floatx4;

#define MFMA16(a, b, c) __builtin_amdgcn_mfma_f32_16x16x32_bf16((a), (b), (c), 0, 0, 0)

// Raw barrier: DS-ordering only; global register loads stay in flight.
#define BARRIER_DS() do {                                          \
    asm volatile("s_waitcnt lgkmcnt(0)" ::: "memory");             \
    __builtin_amdgcn_s_barrier();                                  \
} while (0)

__device__ __forceinline__ ushort_t f2b(float f) {
    uint_t b = __float_as_uint(f);
    b += 0x7FFFu + ((b >> 16) & 1u);   // RNE to bf16
    return (ushort_t)(b >> 16);
}

__device__ __forceinline__ short8 pack8(floatx4 a, floatx4 b) {
    short8 r;
    r[0] = (short)f2b(a[0]); r[1] = (short)f2b(a[1]);
    r[2] = (short)f2b(a[2]); r[3] = (short)f2b(a[3]);
    r[4] = (short)f2b(b[0]); r[5] = (short)f2b(b[1]);
    r[6] = (short)f2b(b[2]); r[7] = (short)f2b(b[3]);
    return r;
}

#define BB 4
#define CK 64
#define NN 8192
#define MM 1024
#define CV 512
#define NSTEP 128     // 64-token steps over full n-range

// ---------------------------------------------------------------------------
// K1 (single kernel): grid 512 = mt16(16) x cs(8) x b(4); block 256 = 4 waves.
// Per 64-token step (wave w owns n-strip step*64 + w*16 + l15 for GEMM1):
//   prefetch next step: 16 scalar fp32 mk loads (c = quad*8+j and +32; lane-
//     coalesced over l15) -> FN[16]; 4x16B mv fp32 loads -> MN.
//   convert current FC: asq = (sum_i FC[i]^2 + shfl_xor 16,32) * 0.125;
//     kc0/kc1 = f2b-packed short8 (R15-pinned B-frag slots).
//   GEMM1 (R15-pinned): A=Q regs, B=kc -> D[m=quad*4+r][n=l15];
//     p = exp(d/4 - asq); f2b b16 -> lds_p[m][n] pitch 72.  BARRIER_DS.
//   GEMM2 (R15-pinned): A=pack8(mv fp32 regs), B=P b128 from lds_p ->
//     acc (c=quad*4+r, m=mt*16+l15); wave owns c-strip c0+w*16.  BARRIER_DS.
// Epilogue: dpart shfl-reduce over l15, atomicAdd dn[64], normalize, store.
// ---------------------------------------------------------------------------

#define PF(FN, MN0, MN1, MN2, MN3, sv) do {                                     \
    size_t no = (size_t)(sv) * 64;                                              \
    _Pragma("unroll")                                                           \
    for (int j = 0; j < 8; j++) {                                               \
        FN[j]     = kb[(size_t)j * NN + no];                                    \
        FN[j + 8] = kb[(size_t)(32 + j) * NN + no];                             \
    }                                                                           \
    const float* mp = mvbase + no;                                              \
    MN0 = *(const floatx4*)(mp);                                                \
    MN1 = *(const floatx4*)(mp + 4);                                            \
    MN2 = *(const floatx4*)(mp + 32);                                           \
    MN3 = *(const floatx4*)(mp + 36);                                           \
} while (0)

#define STEPX(FC, MC0, MC1, MC2, MC3, FN, MN0, MN1, MN2, MN3, stepv) do {       \
    if ((stepv) + 1 < NSTEP) { PF(FN, MN0, MN1, MN2, MN3, (stepv) + 1); }       \
    /* ---- convert current K set + in-wave asq ---- */                         \
    float sq = 0.f;                                                             \
    _Pragma("unroll")                                                           \
    for (int i = 0; i < 16; i++) sq = fmaf(FC[i], FC[i], sq);                   \
    sq += __shfl_xor(sq, 16, 64);                                               \
    sq += __shfl_xor(sq, 32, 64);                                               \
    float AC = sq * 0.125f;                                                     \
    short8 kc0, kc1;                                                            \
    _Pragma("unroll")                                                           \
    for (int j = 0; j < 8; j++) {                                               \
        kc0[j] = (short)f2b(FC[j]);                                             \
        kc1[j] = (short)f2b(FC[j + 8]);                                         \
    }                                                                           \
    /* ---- GEMM1 -> exp -> P(bf16) b16 stores + denom partial ---- */          \
    _Pragma("unroll")                                                           \
    for (int mt = 0; mt < 4; mt++) {                                            \
        floatx4 d = (floatx4){0.f, 0.f, 0.f, 0.f};                              \
        d = MFMA16(qb0[mt], kc0, d);                                            \
        d = MFMA16(qb1[mt], kc1, d);                                            \
        _Pragma("unroll")                                                       \
        for (int r = 0; r < 4; r++) {                                           \
            float p = __expf(d[r] * 0.25f - AC);                                \
            dpart[mt][r] += p;                                                  \
            lds_p[(mt * 16 + quad * 4 + r) * 72 + w * 16 + l15] = f2b(p);       \
        }                                                                       \
    }                                                                           \
    BARRIER_DS();   /* P stores visible; global prefetch stays in flight */     \
    {                                                                           \
        short8 va0 = pack8(MC0, MC1);                                           \
        short8 va1 = pack8(MC2, MC3);                                           \
        _Pragma("unroll")                                                       \
        for (int mt = 0; mt < 4; mt++) {                                        \
            short8 pb0 = *(const short8*)&lds_p[(mt * 16 + l15) * 72 + quad * 8];        \
            short8 pb1 = *(const short8*)&lds_p[(mt * 16 + l15) * 72 + 32 + quad * 8];   \
            acc[mt] = MFMA16(va0, pb0, acc[mt]);                                \
            acc[mt] = MFMA16(va1, pb1, acc[mt]);                                \
        }                                                                       \
    }                                                                           \
    BARRIER_DS();   /* P consumed before next overwrite */                      \
} while (0)

__global__ __launch_bounds__(256, 2) void k_main(const float* __restrict__ qk,
                                                 const float* __restrict__ mk,
                                                 const float* __restrict__ mv,
                                                 float* __restrict__ out) {
    __shared__ __align__(16) ushort_t lds_p[64 * 72];   // 9 KiB, P [m_loc][n_loc]
    __shared__ float dn[64];                            // denom per m_loc

    int bx = blockIdx.x;
    int mt16 = bx >> 5;          // 0..15
    int cs = (bx >> 2) & 7;      // 0..7  (bx%8 const per (cs,b): XCD grouping)
    int b = bx & 3;              // 0..3
    int c0 = cs * 64;
    int m0 = mt16 * 64;

    int tid = threadIdx.x;
    int w = tid >> 6;
    int lane = tid & 63;
    int quad = lane >> 4;
    int l15 = lane & 15;

    if (tid < 64) dn[tid] = 0.f;   // ordered before epilogue by loop barriers

    // ---- Q fragments: 4 m-tiles x K=64 (A-operand rows m = mt*16 + l15) ----
    short8 qb0[4], qb1[4];
#pragma unroll
    for (int mt = 0; mt < 4; mt++) {
#pragma unroll
        for (int j = 0; j < 8; j++) {
            qb0[mt][j] = (short)f2b(qk[(size_t)(b * CK + quad * 8 + j) * MM + m0 + mt * 16 + l15]);
            qb1[mt][j] = (short)f2b(qk[(size_t)(b * CK + 32 + quad * 8 + j) * MM + m0 + mt * 16 + l15]);
        }
    }

    // ---- per-lane stream bases ----
    // K: mk[(b*64 + quad*8 + j)*NN + n], n = step*64 + w*16 + l15
    const float* kb     = mk + ((size_t)(b * CK) + quad * 8) * NN + w * 16 + l15;
    const float* mvbase = mv + ((size_t)(b * CV + c0 + w * 16 + l15)) * NN + quad * 8;

    floatx4 acc[4];
#pragma unroll
    for (int i = 0; i < 4; i++) acc[i] = (floatx4){0.f, 0.f, 0.f, 0.f};
    float dpart[4][4];
#pragma unroll
    for (int i = 0; i < 4; i++)
#pragma unroll
        for (int j = 0; j < 4; j++) dpart[i][j] = 0.f;

    // ---- prologue: step-0 operands into set A ----
    float fA[16], fB[16];
    floatx4 mA0, mA1, mA2, mA3, mB0, mB1, mB2, mB3;
    PF(fA, mA0, mA1, mA2, mA3, 0);

    for (int sp = 0; sp < NSTEP / 2; sp++) {
        STEPX(fA, mA0, mA1, mA2, mA3, fB, mB0, mB1, mB2, mB3, sp * 2);
        STEPX(fB, mB0, mB1, mB2, mB3, fA, mA0, mA1, mA2, mA3, sp * 2 + 1);
    }

    // ---- epilogue: denominator (reduce over l15, cross-wave atomicAdd) ----
#pragma unroll
    for (int mt = 0; mt < 4; mt++) {
#pragma unroll
        for (int r = 0; r < 4; r++) {
            float s = dpart[mt][r];
            s += __shfl_xor(s, 1, 64);
            s += __shfl_xor(s, 2, 64);
            s += __shfl_xor(s, 4, 64);
            s += __shfl_xor(s, 8, 64);
            if (l15 == 0) atomicAdd(&dn[mt * 16 + quad * 4 + r], s);
        }
    }
    __syncthreads();

    float rdm[4];
#pragma unroll
    for (int mt = 0; mt < 4; mt++) rdm[mt] = 1.0f / dn[mt * 16 + l15];
#pragma unroll
    for (int mt = 0; mt < 4; mt++) {
#pragma unroll
        for (int r = 0; r < 4; r++) {
            size_t o = (size_t)(b * CV + c0 + w * 16 + quad * 4 + r) * MM
                     + m0 + mt * 16 + l15;
            out[o] = acc[mt][r] * rdm[mt];
        }
    }
}

// ---------------------------------------------------------------------------
// launch — inputs identified BY SIZE. Single kernel, no prep.
// ---------------------------------------------------------------------------
extern "C" void kernel_launch(void* const* d_in, const int* in_sizes, int n_in,
                              void* d_out, int out_size, void* d_ws, size_t ws_size,
                              hipStream_t stream) {
    const float* mk = nullptr;   // 2,097,152
    const float* qk = nullptr;   //   262,144
    const float* mv = nullptr;   // 16,777,216
    for (int i = 0; i < n_in; i++) {
        if (in_sizes[i] == BB * CK * NN)      mk = (const float*)d_in[i];
        else if (in_sizes[i] == BB * CK * MM) qk = (const float*)d_in[i];
        else if (in_sizes[i] == BB * CV * NN) mv = (const float*)d_in[i];
    }
    float* out = (float*)d_out;
    (void)d_ws; (void)ws_size; (void)out_size;

    k_main<<<16 * 8 * BB, 256, 0, stream>>>(qk, mk, mv, out);
}